// Round 7
// baseline (516.046 us; speedup 1.0000x reference)
//
#include <hip/hip_runtime.h>

// ---------------------------------------------------------------------------
// Precision strategy (R6): absmax has been BIT-IDENTICAL (3.125e-2) across
// fp64-exact and several fp32 orderings -> the error is the reference's own
// fixed fp32 flip-set vs truth; only bit-replication of the ref's ordering
// can pass. Model: jax reference re-executed on CPU (XLA-CPU / Eigen):
//  - conv: Eigen spatial conv (NHWC/HWIO), im2col K-order (ky,kx,ic) with
//    ic FASTEST; K=27/288 <= kc -> one sequential FMA chain per output,
//    acc starts at 0; bias after as one rounded add.
//  - dot: Eigen gebp, f32 AVX2 blocking kc = 288 (evaluateProductBlocking-
//    SizesHeuristic: min((32K-384)/112, 320) floor8 = 288). Per C element:
//    k-sequential FMA chain per 288-panel; panels combined with one rounded
//    add each (C = P0; C += Pc). fc1: 14x288 + 64. fc2: 288/288/288/136.
//  - elementwise recurrence: per-op rounding, no FMA contraction.
// ---------------------------------------------------------------------------

// ---------------------------------------------------------------------------
// Kernel 1: conv1 (3->32) + bias + ReLU + 2x2 maxpool. One block per image.
// Chain order per output: ky -> kx -> ic (ic innermost), single seq chain.
// ---------------------------------------------------------------------------
__global__ void __launch_bounds__(256) conv1_pool(
    const float* __restrict__ x, const float* __restrict__ w,
    const float* __restrict__ bias, float* __restrict__ p1) {
  const int b = blockIdx.x;
  __shared__ float sx[3 * 34 * 34];
  const float* xb = x + (size_t)b * 3072;
  for (int i = threadIdx.x; i < 3 * 34 * 34; i += 256) sx[i] = 0.0f;
  __syncthreads();
  for (int i = threadIdx.x; i < 3072; i += 256) {
    int ic = i >> 10, y = (i >> 5) & 31, xx = i & 31;
    sx[ic * 1156 + (y + 1) * 34 + (xx + 1)] = xb[i];
  }
  __syncthreads();

  const int px = threadIdx.x & 15, py = threadIdx.x >> 4;
  float xr[3][4][4];
#pragma unroll
  for (int ic = 0; ic < 3; ic++)
#pragma unroll
    for (int r = 0; r < 4; r++)
#pragma unroll
      for (int c = 0; c < 4; c++)
        xr[ic][r][c] = sx[ic * 1156 + (2 * py + r) * 34 + (2 * px + c)];

  float* outp = p1 + (size_t)b * 8192 + py * 16 + px;
  for (int oc = 0; oc < 32; oc++) {
    const float* wo = w + oc * 27;
    float a0 = 0.0f, a1 = 0.0f, a2 = 0.0f, a3 = 0.0f;
#pragma unroll
    for (int ky = 0; ky < 3; ky++)
#pragma unroll
      for (int kx = 0; kx < 3; kx++)
#pragma unroll
        for (int ic = 0; ic < 3; ic++) {  // ic innermost (HWIO im2col order)
          float wv = wo[ic * 9 + ky * 3 + kx];
          a0 = fmaf(wv, xr[ic][ky][kx], a0);
          a1 = fmaf(wv, xr[ic][ky][kx + 1], a1);
          a2 = fmaf(wv, xr[ic][ky + 1][kx], a2);
          a3 = fmaf(wv, xr[ic][ky + 1][kx + 1], a3);
        }
    float bv = bias[oc];
    a0 = fmaxf(__fadd_rn(a0, bv), 0.0f);
    a1 = fmaxf(__fadd_rn(a1, bv), 0.0f);
    a2 = fmaxf(__fadd_rn(a2, bv), 0.0f);
    a3 = fmaxf(__fadd_rn(a3, bv), 0.0f);
    outp[oc * 256] = fmaxf(fmaxf(a0, a1), fmaxf(a2, a3));
  }
}

// ---------------------------------------------------------------------------
// Kernel 2: conv2 (32->64) + bias + ReLU + pool. One block per image, padded
// input 32x18x18 in LDS. 4 waves x 16 ocs (wave-uniform oc -> scalar weight
// loads). Chain order per output: ky -> kx -> ic (ic fastest), K=288 = one
// Eigen kc panel -> single sequential chain.
// ---------------------------------------------------------------------------
__global__ void __launch_bounds__(256) conv2_pool(
    const float* __restrict__ p1, const float* __restrict__ w,
    const float* __restrict__ bias, float* __restrict__ p2) {
  const int b = blockIdx.x;
  __shared__ float sx[32 * 18 * 18];  // 41472 B
  const float* xb = p1 + (size_t)b * 8192;
  for (int i = threadIdx.x; i < 32 * 18 * 18; i += 256) sx[i] = 0.0f;
  __syncthreads();
  for (int i = threadIdx.x; i < 8192; i += 256) {
    int ic = i >> 8, y = (i >> 4) & 15, xx = i & 15;
    sx[ic * 324 + (y + 1) * 18 + (xx + 1)] = xb[i];
  }
  __syncthreads();

  const int t = threadIdx.x;
  const int px = t & 7, py = (t >> 3) & 7;
  const int g = __builtin_amdgcn_readfirstlane(t >> 6);  // wave 0..3

  float acc[16][4];
#pragma unroll
  for (int i = 0; i < 16; i++)
    acc[i][0] = acc[i][1] = acc[i][2] = acc[i][3] = 0.0f;

#pragma unroll
  for (int ky = 0; ky < 3; ky++) {
#pragma unroll
    for (int kx = 0; kx < 3; kx++) {
      const int r0 = (2 * py + ky) * 18 + 2 * px + kx;
      const int r1 = r0 + 18;
#pragma unroll 4
      for (int ic = 0; ic < 32; ic++) {  // ic innermost
        float x00 = sx[ic * 324 + r0];
        float x01 = sx[ic * 324 + r0 + 1];
        float x10 = sx[ic * 324 + r1];
        float x11 = sx[ic * 324 + r1 + 1];
        const float* wp = w + (size_t)(g * 16) * 288 + ic * 9 + ky * 3 + kx;
#pragma unroll
        for (int i = 0; i < 16; i++) {
          float wv = wp[i * 288];
          acc[i][0] = fmaf(wv, x00, acc[i][0]);
          acc[i][1] = fmaf(wv, x01, acc[i][1]);
          acc[i][2] = fmaf(wv, x10, acc[i][2]);
          acc[i][3] = fmaf(wv, x11, acc[i][3]);
        }
      }
    }
  }

  float* outb = p2 + (size_t)b * 4096;
#pragma unroll
  for (int i = 0; i < 16; i++) {
    float bv = bias[g * 16 + i];
    float a0 = fmaxf(__fadd_rn(acc[i][0], bv), 0.0f);
    float a1 = fmaxf(__fadd_rn(acc[i][1], bv), 0.0f);
    float a2 = fmaxf(__fadd_rn(acc[i][2], bv), 0.0f);
    float a3 = fmaxf(__fadd_rn(acc[i][3], bv), 0.0f);
    outb[(g * 16 + i) * 64 + py * 8 + px] = fmaxf(fmaxf(a0, a1), fmaxf(a2, a3));
  }
}

// ---------------------------------------------------------------------------
// Kernel 3: fc1 with Eigen gebp K-blocking: kc=288. K=4096 -> panels
// [0,288),[288,576),...,[4032,4096); each panel a sequential fp32 FMA chain
// from 0; panels combined with one rounded add each (C = P0; C += Pc).
// Bias added after. 64x64 tile, 256 thr, 4x4 microtile.
// ---------------------------------------------------------------------------
__global__ void __launch_bounds__(256) fc1_gemm(
    const float* __restrict__ A,    // h [512,4096]
    const float* __restrict__ W,    // [1000,4096]
    const float* __restrict__ bias, // [1000]
    float* __restrict__ cur1) {     // [512,1000]
  __shared__ __align__(16) float As[16][68];
  __shared__ __align__(16) float Bs[16][68];
  const int t = threadIdx.x;
  const int m0 = blockIdx.x * 64, n0 = blockIdx.y * 64;
  const int lm = t >> 2, lk = (t & 3) * 4;
  const int nr = n0 + lm;
  const float* Ap = A + (size_t)(m0 + lm) * 4096 + lk;
  const float* Bp = W + (size_t)(nr < 1000 ? nr : 0) * 4096 + lk;
  const int tx = t & 15, ty = t >> 4;

  float acc[4][4] = {};  // current K-panel partial (register chain)
  float tot[4][4] = {};  // combined C (rounded add per panel boundary)
  for (int kk = 0; kk < 4096; kk += 16) {
    float4 a4 = *(const float4*)Ap;
    float4 b4 = *(const float4*)Bp;
    As[lk + 0][lm] = a4.x; As[lk + 1][lm] = a4.y;
    As[lk + 2][lm] = a4.z; As[lk + 3][lm] = a4.w;
    Bs[lk + 0][lm] = b4.x; Bs[lk + 1][lm] = b4.y;
    Bs[lk + 2][lm] = b4.z; Bs[lk + 3][lm] = b4.w;
    __syncthreads();
#pragma unroll
    for (int k = 0; k < 16; k++) {
      float4 av = *(const float4*)&As[k][tx * 4];
      float4 bv = *(const float4*)&Bs[k][ty * 4];
      acc[0][0] = fmaf(av.x, bv.x, acc[0][0]);
      acc[0][1] = fmaf(av.x, bv.y, acc[0][1]);
      acc[0][2] = fmaf(av.x, bv.z, acc[0][2]);
      acc[0][3] = fmaf(av.x, bv.w, acc[0][3]);
      acc[1][0] = fmaf(av.y, bv.x, acc[1][0]);
      acc[1][1] = fmaf(av.y, bv.y, acc[1][1]);
      acc[1][2] = fmaf(av.y, bv.z, acc[1][2]);
      acc[1][3] = fmaf(av.y, bv.w, acc[1][3]);
      acc[2][0] = fmaf(av.z, bv.x, acc[2][0]);
      acc[2][1] = fmaf(av.z, bv.y, acc[2][1]);
      acc[2][2] = fmaf(av.z, bv.z, acc[2][2]);
      acc[2][3] = fmaf(av.z, bv.w, acc[2][3]);
      acc[3][0] = fmaf(av.w, bv.x, acc[3][0]);
      acc[3][1] = fmaf(av.w, bv.y, acc[3][1]);
      acc[3][2] = fmaf(av.w, bv.z, acc[3][2]);
      acc[3][3] = fmaf(av.w, bv.w, acc[3][3]);
    }
    __syncthreads();
    Ap += 16; Bp += 16;

    const int knext = kk + 16;
    if ((knext % 288) == 0 || knext == 4096) {  // Eigen kc=288 panel boundary
#pragma unroll
      for (int i = 0; i < 4; i++)
#pragma unroll
        for (int j = 0; j < 4; j++) {
          tot[i][j] = (knext == 288) ? acc[i][j]                   // C = P0
                                     : __fadd_rn(tot[i][j], acc[i][j]);  // C += Pc
          acc[i][j] = 0.0f;
        }
    }
  }

#pragma unroll
  for (int i = 0; i < 4; i++)
#pragma unroll
    for (int j = 0; j < 4; j++) {
      int n = n0 + ty * 4 + j;
      if (n < 1000)
        cur1[(size_t)(m0 + tx * 4 + i) * 1000 + n] =
            __fadd_rn(tot[i][j], bias[n]);
    }
}

// ---------------------------------------------------------------------------
// Kernel 4: fused 10-step SNN. One block per batch row. cur2 emulates Eigen
// gebp K=1000 blocked kc=288: four chains [0,288),[288,576),[576,864),
// [864,1000) on 4 threads per output, combined in panel order with rounded
// adds, then +bias. Recurrence per-op rounded.
// ---------------------------------------------------------------------------
__global__ void __launch_bounds__(256) snn_loop(
    const float* __restrict__ cur1g,  // [512,1000]
    const float* __restrict__ fc2_w,  // [10,1000]
    const float* __restrict__ fc2_b,  // [10]
    float* __restrict__ out) {        // [102400]
  const int b = blockIdx.x;
  const int t = threadIdx.x;
  __shared__ float w2[10 * 1000];
  __shared__ float spks[1024];
  __shared__ float red[10][4];

  for (int i = t; i < 10000; i += 256) w2[i] = fc2_w[i];

  float cur1[4], mem1[4];
#pragma unroll
  for (int q = 0; q < 4; q++) {
    int j = t + q * 256;
    cur1[q] = (j < 1000) ? cur1g[(size_t)b * 1000 + j] : 0.0f;
    mem1[q] = 0.0f;
  }
  float m2 = 0.0f;  // live only for t < 10
  __syncthreads();

  const int o4 = t >> 2, c4 = t & 3;  // for t<40: output o4, K-panel c4
  const int jlo = c4 * 288, jhi = (c4 == 3) ? 1000 : jlo + 288;

  for (int s = 0; s < 10; s++) {
    // mem1 = ((0.95f*mem1) + cur1) - reset, each op rounded separately
#pragma unroll
    for (int q = 0; q < 4; q++) {
      int j = t + q * 256;
      float m = mem1[q];
      float reset = (m > 1.0f) ? 1.0f : 0.0f;
      float t1 = __fmul_rn(0.95f, m);
      float t2 = __fadd_rn(t1, cur1[q]);
      m = __fsub_rn(t2, reset);
      mem1[q] = m;
      spks[j] = (m > 1.0f) ? 1.0f : 0.0f;  // j>=1000: m stays 0 -> 0
    }
    __syncthreads();

    if (t < 40) {  // four independent panel chains per output
      float acc = 0.0f;
      const float* wrow = w2 + o4 * 1000;
      for (int j = jlo; j < jhi; j++) acc = fmaf(spks[j], wrow[j], acc);
      red[o4][c4] = acc;
    }
    __syncthreads();

    if (t < 10) {
      float tot = red[t][0];                    // C = P0
      tot = __fadd_rn(tot, red[t][1]);          // C += P1
      tot = __fadd_rn(tot, red[t][2]);          // C += P2
      tot = __fadd_rn(tot, red[t][3]);          // C += P3
      float c2 = __fadd_rn(tot, fc2_b[t]);      // + bias
      float r2 = (m2 > 1.0f) ? 1.0f : 0.0f;
      float u1 = __fmul_rn(0.95f, m2);
      float u2 = __fadd_rn(u1, c2);
      m2 = __fsub_rn(u2, r2);
      out[s * 5120 + b * 10 + t] = (m2 > 1.0f) ? 1.0f : 0.0f;  // spk2
      out[51200 + s * 5120 + b * 10 + t] = m2;                  // mem2
    }
    __syncthreads();
  }
}

// ---------------------------------------------------------------------------
// Launch. Workspace (26 MB): [0,16M) p1, [16M,24M) h, [24M,26M) cur1.
// ---------------------------------------------------------------------------
extern "C" void kernel_launch(void* const* d_in, const int* in_sizes, int n_in,
                              void* d_out, int out_size, void* d_ws,
                              size_t ws_size, hipStream_t stream) {
  const float* x   = (const float*)d_in[0];
  const float* c1w = (const float*)d_in[1];
  const float* c1b = (const float*)d_in[2];
  const float* c2w = (const float*)d_in[3];
  const float* c2b = (const float*)d_in[4];
  const float* f1w = (const float*)d_in[5];
  const float* f1b = (const float*)d_in[6];
  const float* f2w = (const float*)d_in[7];
  const float* f2b = (const float*)d_in[8];
  float* out = (float*)d_out;

  char* ws = (char*)d_ws;
  float* p1   = (float*)(ws);             // [512,32,256] = 16 MB
  float* h    = (float*)(ws + 16777216);  // [512,4096]   =  8 MB
  float* cur1 = (float*)(ws + 25165824);  // [512,1000]   =  2 MB

  conv1_pool<<<512, 256, 0, stream>>>(x, c1w, c1b, p1);
  conv2_pool<<<512, 256, 0, stream>>>(p1, c2w, c2b, h);
  fc1_gemm<<<dim3(8, 16), 256, 0, stream>>>(h, f1w, f1b, cur1);
  snn_loop<<<512, 256, 0, stream>>>(cur1, f2w, f2b, out);
}

// Round 9
// 380.273 us; speedup vs baseline: 1.3570x; 1.3570x over previous
//
#include <hip/hip_runtime.h>

// ---------------------------------------------------------------------------
// R8 = R7 resubmit (R7 bench died to container infra, not kernel).
// Semantics frozen from R6 (PASSED, absmax 1.95e-3) — Eigen/XLA-CPU emulation:
//  - conv: im2col K-order (ky,kx,ic) ic fastest, one sequential FMA chain,
//    bias after as one rounded add.
//  - fc1: Eigen gebp kc=288 -> 15 independent panel chains (14x288 + 64),
//    combined IN ORDER with one rounded add each, then +bias.
//  - fc2: kc=288 -> 4 panel chains (288/288/288/136), same combine.
//  - recurrence: per-op rounding (__fmul_rn/__fadd_rn/__fsub_rn).
// Perf change vs R6: fc1 was 128 blocks / 5.6% occupancy / 13.5% VALUBusy,
// 230 us. Panels are independent -> split-K over z=15 (960 blocks), 128x64
// tile, 8x4 microtile; ordered combine moved to snn_loop init (bit-identical).
// ---------------------------------------------------------------------------

// ---------------------------------------------------------------------------
// Kernel 1: conv1 (3->32) + bias + ReLU + 2x2 maxpool. One block per image.
// Chain order: ky -> kx -> ic (ic innermost). UNCHANGED from R6.
// ---------------------------------------------------------------------------
__global__ void __launch_bounds__(256) conv1_pool(
    const float* __restrict__ x, const float* __restrict__ w,
    const float* __restrict__ bias, float* __restrict__ p1) {
  const int b = blockIdx.x;
  __shared__ float sx[3 * 34 * 34];
  const float* xb = x + (size_t)b * 3072;
  for (int i = threadIdx.x; i < 3 * 34 * 34; i += 256) sx[i] = 0.0f;
  __syncthreads();
  for (int i = threadIdx.x; i < 3072; i += 256) {
    int ic = i >> 10, y = (i >> 5) & 31, xx = i & 31;
    sx[ic * 1156 + (y + 1) * 34 + (xx + 1)] = xb[i];
  }
  __syncthreads();

  const int px = threadIdx.x & 15, py = threadIdx.x >> 4;
  float xr[3][4][4];
#pragma unroll
  for (int ic = 0; ic < 3; ic++)
#pragma unroll
    for (int r = 0; r < 4; r++)
#pragma unroll
      for (int c = 0; c < 4; c++)
        xr[ic][r][c] = sx[ic * 1156 + (2 * py + r) * 34 + (2 * px + c)];

  float* outp = p1 + (size_t)b * 8192 + py * 16 + px;
  for (int oc = 0; oc < 32; oc++) {
    const float* wo = w + oc * 27;
    float a0 = 0.0f, a1 = 0.0f, a2 = 0.0f, a3 = 0.0f;
#pragma unroll
    for (int ky = 0; ky < 3; ky++)
#pragma unroll
      for (int kx = 0; kx < 3; kx++)
#pragma unroll
        for (int ic = 0; ic < 3; ic++) {  // ic innermost (HWIO im2col order)
          float wv = wo[ic * 9 + ky * 3 + kx];
          a0 = fmaf(wv, xr[ic][ky][kx], a0);
          a1 = fmaf(wv, xr[ic][ky][kx + 1], a1);
          a2 = fmaf(wv, xr[ic][ky + 1][kx], a2);
          a3 = fmaf(wv, xr[ic][ky + 1][kx + 1], a3);
        }
    float bv = bias[oc];
    a0 = fmaxf(__fadd_rn(a0, bv), 0.0f);
    a1 = fmaxf(__fadd_rn(a1, bv), 0.0f);
    a2 = fmaxf(__fadd_rn(a2, bv), 0.0f);
    a3 = fmaxf(__fadd_rn(a3, bv), 0.0f);
    outp[oc * 256] = fmaxf(fmaxf(a0, a1), fmaxf(a2, a3));
  }
}

// ---------------------------------------------------------------------------
// Kernel 2: conv2 (32->64) + bias + ReLU + pool. UNCHANGED from R6.
// ---------------------------------------------------------------------------
__global__ void __launch_bounds__(256) conv2_pool(
    const float* __restrict__ p1, const float* __restrict__ w,
    const float* __restrict__ bias, float* __restrict__ p2) {
  const int b = blockIdx.x;
  __shared__ float sx[32 * 18 * 18];  // 41472 B
  const float* xb = p1 + (size_t)b * 8192;
  for (int i = threadIdx.x; i < 32 * 18 * 18; i += 256) sx[i] = 0.0f;
  __syncthreads();
  for (int i = threadIdx.x; i < 8192; i += 256) {
    int ic = i >> 8, y = (i >> 4) & 15, xx = i & 15;
    sx[ic * 324 + (y + 1) * 18 + (xx + 1)] = xb[i];
  }
  __syncthreads();

  const int t = threadIdx.x;
  const int px = t & 7, py = (t >> 3) & 7;
  const int g = __builtin_amdgcn_readfirstlane(t >> 6);  // wave 0..3

  float acc[16][4];
#pragma unroll
  for (int i = 0; i < 16; i++)
    acc[i][0] = acc[i][1] = acc[i][2] = acc[i][3] = 0.0f;

#pragma unroll
  for (int ky = 0; ky < 3; ky++) {
#pragma unroll
    for (int kx = 0; kx < 3; kx++) {
      const int r0 = (2 * py + ky) * 18 + 2 * px + kx;
      const int r1 = r0 + 18;
#pragma unroll 4
      for (int ic = 0; ic < 32; ic++) {  // ic innermost
        float x00 = sx[ic * 324 + r0];
        float x01 = sx[ic * 324 + r0 + 1];
        float x10 = sx[ic * 324 + r1];
        float x11 = sx[ic * 324 + r1 + 1];
        const float* wp = w + (size_t)(g * 16) * 288 + ic * 9 + ky * 3 + kx;
#pragma unroll
        for (int i = 0; i < 16; i++) {
          float wv = wp[i * 288];
          acc[i][0] = fmaf(wv, x00, acc[i][0]);
          acc[i][1] = fmaf(wv, x01, acc[i][1]);
          acc[i][2] = fmaf(wv, x10, acc[i][2]);
          acc[i][3] = fmaf(wv, x11, acc[i][3]);
        }
      }
    }
  }

  float* outb = p2 + (size_t)b * 4096;
#pragma unroll
  for (int i = 0; i < 16; i++) {
    float bv = bias[g * 16 + i];
    float a0 = fmaxf(__fadd_rn(acc[i][0], bv), 0.0f);
    float a1 = fmaxf(__fadd_rn(acc[i][1], bv), 0.0f);
    float a2 = fmaxf(__fadd_rn(acc[i][2], bv), 0.0f);
    float a3 = fmaxf(__fadd_rn(acc[i][3], bv), 0.0f);
    outb[(g * 16 + i) * 64 + py * 8 + px] = fmaxf(fmaxf(a0, a1), fmaxf(a2, a3));
  }
}

// ---------------------------------------------------------------------------
// Kernel 3: fc1 panel GEMM, split-K over Eigen kc=288 panels.
// grid (4, 16, 15): z = panel (14x288 + one 64-tail). Each block: 128x64
// C-tile, 256 threads, 8m x 4n microtile. Each output element's panel chain
// is k-sequential fp32 FMA from 0 — bit-identical to R6's in-loop panels.
// part[z][m][n] holds the panel partial; combine happens in snn_loop.
// ---------------------------------------------------------------------------
__global__ void __launch_bounds__(256) fc1_panel(
    const float* __restrict__ A,   // h [512,4096]
    const float* __restrict__ W,   // [1000,4096]
    float* __restrict__ part) {    // [15,512,1000]
  __shared__ __align__(16) float As[16][132];  // 8448 B
  __shared__ __align__(16) float Bs[16][68];   // 4352 B
  const int t = threadIdx.x;
  const int m0 = blockIdx.x * 128, n0 = blockIdx.y * 64;
  const int z = blockIdx.z;
  const int k0 = z * 288;
  const int L = (z == 14) ? 64 : 288;

  // A staging: thread -> (row lmA = t>>1 of 128, k-offset lkA = (t&1)*8)
  const int lmA = t >> 1, lkA = (t & 1) * 8;
  // B staging: thread -> (row lmB = t>>2 of 64, k-offset lkB = (t&3)*4)
  const int lmB = t >> 2, lkB = (t & 3) * 4;
  const int nr = n0 + lmB;
  const float* Ap = A + (size_t)(m0 + lmA) * 4096 + k0 + lkA;
  const float* Bp = W + (size_t)(nr < 1000 ? nr : 0) * 4096 + k0 + lkB;
  const int tx = t & 15, ty = t >> 4;  // tx: m-group (8 rows), ty: n-group (4)

  float acc[8][4];
#pragma unroll
  for (int i = 0; i < 8; i++)
#pragma unroll
    for (int j = 0; j < 4; j++) acc[i][j] = 0.0f;

  for (int kk = 0; kk < L; kk += 16) {
    float4 a0 = *(const float4*)Ap;
    float4 a1 = *(const float4*)(Ap + 4);
    float4 b4 = *(const float4*)Bp;
    As[lkA + 0][lmA] = a0.x; As[lkA + 1][lmA] = a0.y;
    As[lkA + 2][lmA] = a0.z; As[lkA + 3][lmA] = a0.w;
    As[lkA + 4][lmA] = a1.x; As[lkA + 5][lmA] = a1.y;
    As[lkA + 6][lmA] = a1.z; As[lkA + 7][lmA] = a1.w;
    Bs[lkB + 0][lmB] = b4.x; Bs[lkB + 1][lmB] = b4.y;
    Bs[lkB + 2][lmB] = b4.z; Bs[lkB + 3][lmB] = b4.w;
    __syncthreads();
#pragma unroll
    for (int k = 0; k < 16; k++) {
      float4 av0 = *(const float4*)&As[k][tx * 8];
      float4 av1 = *(const float4*)&As[k][tx * 8 + 4];
      float4 bv = *(const float4*)&Bs[k][ty * 4];
      float am[8] = {av0.x, av0.y, av0.z, av0.w, av1.x, av1.y, av1.z, av1.w};
#pragma unroll
      for (int i = 0; i < 8; i++) {
        acc[i][0] = fmaf(am[i], bv.x, acc[i][0]);
        acc[i][1] = fmaf(am[i], bv.y, acc[i][1]);
        acc[i][2] = fmaf(am[i], bv.z, acc[i][2]);
        acc[i][3] = fmaf(am[i], bv.w, acc[i][3]);
      }
    }
    __syncthreads();
    Ap += 16; Bp += 16;
  }

  float* pp = part + (size_t)z * 512000;
#pragma unroll
  for (int i = 0; i < 8; i++) {
    const int m = m0 + tx * 8 + i;
#pragma unroll
    for (int j = 0; j < 4; j++) {
      const int n = n0 + ty * 4 + j;
      if (n < 1000) pp[(size_t)m * 1000 + n] = acc[i][j];
    }
  }
}

// ---------------------------------------------------------------------------
// Kernel 4: fused 10-step SNN. One block per batch row. cur1 init does the
// Eigen panel combine: tot = P0; tot += P1 ... += P14 (rounded adds, in
// order), then +bias — bit-identical to R6's fc1 epilogue. fc2 as before:
// 4 panel chains on 4 threads per output, ordered rounded combine, +bias.
// ---------------------------------------------------------------------------
__global__ void __launch_bounds__(256) snn_loop(
    const float* __restrict__ part,   // [15,512,1000]
    const float* __restrict__ fc1_b,  // [1000]
    const float* __restrict__ fc2_w,  // [10,1000]
    const float* __restrict__ fc2_b,  // [10]
    float* __restrict__ out) {        // [102400]
  const int b = blockIdx.x;
  const int t = threadIdx.x;
  __shared__ float w2[10 * 1000];
  __shared__ float spks[1024];
  __shared__ float red[10][4];

  for (int i = t; i < 10000; i += 256) w2[i] = fc2_w[i];

  float cur1[4], mem1[4];
#pragma unroll
  for (int q = 0; q < 4; q++) {
    int j = t + q * 256;
    float c = 0.0f;
    if (j < 1000) {
      const float* pb = part + (size_t)b * 1000 + j;
      float tot = pb[0];                               // C = P0
#pragma unroll
      for (int p = 1; p < 15; p++)
        tot = __fadd_rn(tot, pb[(size_t)p * 512000]);  // C += Pp (in order)
      c = __fadd_rn(tot, fc1_b[j]);                    // + bias
    }
    cur1[q] = c;
    mem1[q] = 0.0f;
  }
  float m2 = 0.0f;  // live only for t < 10
  __syncthreads();

  const int o4 = t >> 2, c4 = t & 3;  // for t<40: output o4, K-panel c4
  const int jlo = c4 * 288, jhi = (c4 == 3) ? 1000 : jlo + 288;

  for (int s = 0; s < 10; s++) {
    // mem1 = ((0.95f*mem1) + cur1) - reset, each op rounded separately
#pragma unroll
    for (int q = 0; q < 4; q++) {
      int j = t + q * 256;
      float m = mem1[q];
      float reset = (m > 1.0f) ? 1.0f : 0.0f;
      float t1 = __fmul_rn(0.95f, m);
      float t2 = __fadd_rn(t1, cur1[q]);
      m = __fsub_rn(t2, reset);
      mem1[q] = m;
      spks[j] = (m > 1.0f) ? 1.0f : 0.0f;  // j>=1000: m stays 0 -> 0
    }
    __syncthreads();

    if (t < 40) {  // four independent panel chains per output
      float acc = 0.0f;
      const float* wrow = w2 + o4 * 1000;
      for (int j = jlo; j < jhi; j++) acc = fmaf(spks[j], wrow[j], acc);
      red[o4][c4] = acc;
    }
    __syncthreads();

    if (t < 10) {
      float tot = red[t][0];                    // C = P0
      tot = __fadd_rn(tot, red[t][1]);          // C += P1
      tot = __fadd_rn(tot, red[t][2]);          // C += P2
      tot = __fadd_rn(tot, red[t][3]);          // C += P3
      float c2 = __fadd_rn(tot, fc2_b[t]);      // + bias
      float r2 = (m2 > 1.0f) ? 1.0f : 0.0f;
      float u1 = __fmul_rn(0.95f, m2);
      float u2 = __fadd_rn(u1, c2);
      m2 = __fsub_rn(u2, r2);
      out[s * 5120 + b * 10 + t] = (m2 > 1.0f) ? 1.0f : 0.0f;  // spk2
      out[51200 + s * 5120 + b * 10 + t] = m2;                  // mem2
    }
    __syncthreads();
  }
}

// ---------------------------------------------------------------------------
// Launch. Workspace (39.1 MB peak, aliased):
//   part [0, 30.72M)      — fc1 panel partials [15,512,1000] fp32
//   p1   [0, 16M)         — conv1 out (dead before fc1 writes part)
//   h    [30.72M, 39.1M)  — conv2 out (live through fc1, above part)
// ---------------------------------------------------------------------------
extern "C" void kernel_launch(void* const* d_in, const int* in_sizes, int n_in,
                              void* d_out, int out_size, void* d_ws,
                              size_t ws_size, hipStream_t stream) {
  const float* x   = (const float*)d_in[0];
  const float* c1w = (const float*)d_in[1];
  const float* c1b = (const float*)d_in[2];
  const float* c2w = (const float*)d_in[3];
  const float* c2b = (const float*)d_in[4];
  const float* f1w = (const float*)d_in[5];
  const float* f1b = (const float*)d_in[6];
  const float* f2w = (const float*)d_in[7];
  const float* f2b = (const float*)d_in[8];
  float* out = (float*)d_out;

  char* ws = (char*)d_ws;
  float* part = (float*)(ws);                        // [15,512,1000] = 30.72 MB
  float* p1   = (float*)(ws);                        // [512,32,256] alias (dead early)
  float* h    = (float*)(ws + (size_t)15 * 512 * 1000 * 4);  // [512,4096] = 8.39 MB

  conv1_pool<<<512, 256, 0, stream>>>(x, c1w, c1b, p1);
  conv2_pool<<<512, 256, 0, stream>>>(p1, c2w, c2b, h);
  fc1_panel<<<dim3(4, 16, 15), 256, 0, stream>>>(h, f1w, part);
  snn_loop<<<512, 256, 0, stream>>>(part, f1b, f2w, f2b, out);
}

// Round 10
// 287.418 us; speedup vs baseline: 1.7955x; 1.3231x over previous
//
#include <hip/hip_runtime.h>

// ---------------------------------------------------------------------------
// R10: numerics frozen from R6/R8 (PASS, absmax 1.95e-3). Perf target this
// round: snn_loop (148 us = serial critical path; non-unrolled LDS-latency-
// bound fc2 loop + bank conflicts + 3 barriers/step).
// Changes (all bit-identical arithmetic):
//  - fc2 weights & spikes in panel-major LDS with stride 289 (odd -> banks
//    conflict-free / 2-way max, free per m136).
//  - fixed-bound unrolled chain loops (288 / 136) so ds_reads pipeline
//    behind the serial FMA chain (~4 cyc/link).
//  - cross-lane panel combine via __shfl within wave 0 (same ordered
//    __fadd_rn sequence) -> 2 barriers/step instead of 3.
// conv1 / conv2 / fc1_panel unchanged.
// ---------------------------------------------------------------------------

// ---------------------------------------------------------------------------
// Kernel 1: conv1 (3->32) + bias + ReLU + 2x2 maxpool. One block per image.
// Chain order: ky -> kx -> ic (ic innermost). UNCHANGED.
// ---------------------------------------------------------------------------
__global__ void __launch_bounds__(256) conv1_pool(
    const float* __restrict__ x, const float* __restrict__ w,
    const float* __restrict__ bias, float* __restrict__ p1) {
  const int b = blockIdx.x;
  __shared__ float sx[3 * 34 * 34];
  const float* xb = x + (size_t)b * 3072;
  for (int i = threadIdx.x; i < 3 * 34 * 34; i += 256) sx[i] = 0.0f;
  __syncthreads();
  for (int i = threadIdx.x; i < 3072; i += 256) {
    int ic = i >> 10, y = (i >> 5) & 31, xx = i & 31;
    sx[ic * 1156 + (y + 1) * 34 + (xx + 1)] = xb[i];
  }
  __syncthreads();

  const int px = threadIdx.x & 15, py = threadIdx.x >> 4;
  float xr[3][4][4];
#pragma unroll
  for (int ic = 0; ic < 3; ic++)
#pragma unroll
    for (int r = 0; r < 4; r++)
#pragma unroll
      for (int c = 0; c < 4; c++)
        xr[ic][r][c] = sx[ic * 1156 + (2 * py + r) * 34 + (2 * px + c)];

  float* outp = p1 + (size_t)b * 8192 + py * 16 + px;
  for (int oc = 0; oc < 32; oc++) {
    const float* wo = w + oc * 27;
    float a0 = 0.0f, a1 = 0.0f, a2 = 0.0f, a3 = 0.0f;
#pragma unroll
    for (int ky = 0; ky < 3; ky++)
#pragma unroll
      for (int kx = 0; kx < 3; kx++)
#pragma unroll
        for (int ic = 0; ic < 3; ic++) {  // ic innermost (HWIO im2col order)
          float wv = wo[ic * 9 + ky * 3 + kx];
          a0 = fmaf(wv, xr[ic][ky][kx], a0);
          a1 = fmaf(wv, xr[ic][ky][kx + 1], a1);
          a2 = fmaf(wv, xr[ic][ky + 1][kx], a2);
          a3 = fmaf(wv, xr[ic][ky + 1][kx + 1], a3);
        }
    float bv = bias[oc];
    a0 = fmaxf(__fadd_rn(a0, bv), 0.0f);
    a1 = fmaxf(__fadd_rn(a1, bv), 0.0f);
    a2 = fmaxf(__fadd_rn(a2, bv), 0.0f);
    a3 = fmaxf(__fadd_rn(a3, bv), 0.0f);
    outp[oc * 256] = fmaxf(fmaxf(a0, a1), fmaxf(a2, a3));
  }
}

// ---------------------------------------------------------------------------
// Kernel 2: conv2 (32->64) + bias + ReLU + pool. UNCHANGED.
// ---------------------------------------------------------------------------
__global__ void __launch_bounds__(256) conv2_pool(
    const float* __restrict__ p1, const float* __restrict__ w,
    const float* __restrict__ bias, float* __restrict__ p2) {
  const int b = blockIdx.x;
  __shared__ float sx[32 * 18 * 18];  // 41472 B
  const float* xb = p1 + (size_t)b * 8192;
  for (int i = threadIdx.x; i < 32 * 18 * 18; i += 256) sx[i] = 0.0f;
  __syncthreads();
  for (int i = threadIdx.x; i < 8192; i += 256) {
    int ic = i >> 8, y = (i >> 4) & 15, xx = i & 15;
    sx[ic * 324 + (y + 1) * 18 + (xx + 1)] = xb[i];
  }
  __syncthreads();

  const int t = threadIdx.x;
  const int px = t & 7, py = (t >> 3) & 7;
  const int g = __builtin_amdgcn_readfirstlane(t >> 6);  // wave 0..3

  float acc[16][4];
#pragma unroll
  for (int i = 0; i < 16; i++)
    acc[i][0] = acc[i][1] = acc[i][2] = acc[i][3] = 0.0f;

#pragma unroll
  for (int ky = 0; ky < 3; ky++) {
#pragma unroll
    for (int kx = 0; kx < 3; kx++) {
      const int r0 = (2 * py + ky) * 18 + 2 * px + kx;
      const int r1 = r0 + 18;
#pragma unroll 4
      for (int ic = 0; ic < 32; ic++) {  // ic innermost
        float x00 = sx[ic * 324 + r0];
        float x01 = sx[ic * 324 + r0 + 1];
        float x10 = sx[ic * 324 + r1];
        float x11 = sx[ic * 324 + r1 + 1];
        const float* wp = w + (size_t)(g * 16) * 288 + ic * 9 + ky * 3 + kx;
#pragma unroll
        for (int i = 0; i < 16; i++) {
          float wv = wp[i * 288];
          acc[i][0] = fmaf(wv, x00, acc[i][0]);
          acc[i][1] = fmaf(wv, x01, acc[i][1]);
          acc[i][2] = fmaf(wv, x10, acc[i][2]);
          acc[i][3] = fmaf(wv, x11, acc[i][3]);
        }
      }
    }
  }

  float* outb = p2 + (size_t)b * 4096;
#pragma unroll
  for (int i = 0; i < 16; i++) {
    float bv = bias[g * 16 + i];
    float a0 = fmaxf(__fadd_rn(acc[i][0], bv), 0.0f);
    float a1 = fmaxf(__fadd_rn(acc[i][1], bv), 0.0f);
    float a2 = fmaxf(__fadd_rn(acc[i][2], bv), 0.0f);
    float a3 = fmaxf(__fadd_rn(acc[i][3], bv), 0.0f);
    outb[(g * 16 + i) * 64 + py * 8 + px] = fmaxf(fmaxf(a0, a1), fmaxf(a2, a3));
  }
}

// ---------------------------------------------------------------------------
// Kernel 3: fc1 panel GEMM, split-K over Eigen kc=288 panels. UNCHANGED.
// grid (4, 16, 15): z = panel (14x288 + one 64-tail). 128x64 C-tile,
// 256 threads, 8m x 4n microtile. part[z][m][n] = panel partial.
// ---------------------------------------------------------------------------
__global__ void __launch_bounds__(256) fc1_panel(
    const float* __restrict__ A,   // h [512,4096]
    const float* __restrict__ W,   // [1000,4096]
    float* __restrict__ part) {    // [15,512,1000]
  __shared__ __align__(16) float As[16][132];  // 8448 B
  __shared__ __align__(16) float Bs[16][68];   // 4352 B
  const int t = threadIdx.x;
  const int m0 = blockIdx.x * 128, n0 = blockIdx.y * 64;
  const int z = blockIdx.z;
  const int k0 = z * 288;
  const int L = (z == 14) ? 64 : 288;

  const int lmA = t >> 1, lkA = (t & 1) * 8;
  const int lmB = t >> 2, lkB = (t & 3) * 4;
  const int nr = n0 + lmB;
  const float* Ap = A + (size_t)(m0 + lmA) * 4096 + k0 + lkA;
  const float* Bp = W + (size_t)(nr < 1000 ? nr : 0) * 4096 + k0 + lkB;
  const int tx = t & 15, ty = t >> 4;

  float acc[8][4];
#pragma unroll
  for (int i = 0; i < 8; i++)
#pragma unroll
    for (int j = 0; j < 4; j++) acc[i][j] = 0.0f;

  for (int kk = 0; kk < L; kk += 16) {
    float4 a0 = *(const float4*)Ap;
    float4 a1 = *(const float4*)(Ap + 4);
    float4 b4 = *(const float4*)Bp;
    As[lkA + 0][lmA] = a0.x; As[lkA + 1][lmA] = a0.y;
    As[lkA + 2][lmA] = a0.z; As[lkA + 3][lmA] = a0.w;
    As[lkA + 4][lmA] = a1.x; As[lkA + 5][lmA] = a1.y;
    As[lkA + 6][lmA] = a1.z; As[lkA + 7][lmA] = a1.w;
    Bs[lkB + 0][lmB] = b4.x; Bs[lkB + 1][lmB] = b4.y;
    Bs[lkB + 2][lmB] = b4.z; Bs[lkB + 3][lmB] = b4.w;
    __syncthreads();
#pragma unroll
    for (int k = 0; k < 16; k++) {
      float4 av0 = *(const float4*)&As[k][tx * 8];
      float4 av1 = *(const float4*)&As[k][tx * 8 + 4];
      float4 bv = *(const float4*)&Bs[k][ty * 4];
      float am[8] = {av0.x, av0.y, av0.z, av0.w, av1.x, av1.y, av1.z, av1.w};
#pragma unroll
      for (int i = 0; i < 8; i++) {
        acc[i][0] = fmaf(am[i], bv.x, acc[i][0]);
        acc[i][1] = fmaf(am[i], bv.y, acc[i][1]);
        acc[i][2] = fmaf(am[i], bv.z, acc[i][2]);
        acc[i][3] = fmaf(am[i], bv.w, acc[i][3]);
      }
    }
    __syncthreads();
    Ap += 16; Bp += 16;
  }

  float* pp = part + (size_t)z * 512000;
#pragma unroll
  for (int i = 0; i < 8; i++) {
    const int m = m0 + tx * 8 + i;
#pragma unroll
    for (int j = 0; j < 4; j++) {
      const int n = n0 + ty * 4 + j;
      if (n < 1000) pp[(size_t)m * 1000 + n] = acc[i][j];
    }
  }
}

// ---------------------------------------------------------------------------
// Kernel 4: fused 10-step SNN, latency-optimized. One block per batch row.
//  - pw: fc2_w panel-major, chain (c*10+o) at stride 289 (odd -> banks
//    spread; worst 2-way = free). spkp: spikes panel-local, stride 289.
//  - chain mapping: lane = c*10 + o (o = t%10, c = t/10) for t < 40.
//  - fc2 chains: fixed-bound unrolled fp32 FMA chains (288/136), bit-equal
//    to R8's loops (same j order, same single accumulator).
//  - panel combine via __shfl within wave 0 in the exact ordered-add
//    sequence (P0; +=P1; +=P2; +=P3), then +bias; recurrence per-op rounded.
//  - 2 barriers per step.
// ---------------------------------------------------------------------------
__global__ void __launch_bounds__(256) snn_loop(
    const float* __restrict__ part,   // [15,512,1000]
    const float* __restrict__ fc1_b,  // [1000]
    const float* __restrict__ fc2_w,  // [10,1000]
    const float* __restrict__ fc2_b,  // [10]
    float* __restrict__ out) {        // [102400]
  const int b = blockIdx.x;
  const int t = threadIdx.x;
  __shared__ float pw[40 * 289];   // 46240 B
  __shared__ float spkp[4 * 289];  //  4624 B

  // fc2_w -> panel-major LDS: pw[(c*10+o)*289 + i] = fc2_w[o*1000 + c*288 + i]
  for (int i = t; i < 40 * 289; i += 256) {
    int chain = i / 289, ii = i - chain * 289;
    int o = chain % 10, c = chain / 10;
    int len = (c == 3) ? 136 : 288;
    pw[i] = (ii < len) ? fc2_w[o * 1000 + c * 288 + ii] : 0.0f;
  }

  // cur1 = ordered Eigen panel combine (C=P0; C+=P1..P14) + bias
  float cur1[4], mem1[4];
#pragma unroll
  for (int q = 0; q < 4; q++) {
    int j = t + q * 256;
    float c = 0.0f;
    if (j < 1000) {
      const float* pb = part + (size_t)b * 1000 + j;
      float tot = pb[0];
#pragma unroll
      for (int p = 1; p < 15; p++)
        tot = __fadd_rn(tot, pb[(size_t)p * 512000]);
      c = __fadd_rn(tot, fc1_b[j]);
    }
    cur1[q] = c;
    mem1[q] = 0.0f;
  }
  float m2 = 0.0f;  // live only for t < 10
  __syncthreads();

  const int o4 = t % 10, c4 = t / 10;  // chain (o4, c4) for t < 40
  const float* wch = &pw[(c4 * 10 + o4) * 289];
  const float* sch = &spkp[c4 * 289];

  for (int s = 0; s < 10; s++) {
    // phase A: mem1 = ((0.95f*mem1) + cur1) - reset, per-op rounded
#pragma unroll
    for (int q = 0; q < 4; q++) {
      int j = t + q * 256;
      float m = mem1[q];
      float reset = (m > 1.0f) ? 1.0f : 0.0f;
      float t1 = __fmul_rn(0.95f, m);
      float t2 = __fadd_rn(t1, cur1[q]);
      m = __fsub_rn(t2, reset);
      mem1[q] = m;
      if (j < 1000) {
        int pc = (j >= 864) ? 3 : ((j >= 576) ? 2 : ((j >= 288) ? 1 : 0));
        spkp[pc * 289 + (j - pc * 288)] = (m > 1.0f) ? 1.0f : 0.0f;
      }
    }
    __syncthreads();

    // phase B: 40 independent panel chains on wave 0 (sequential FMA chain,
    // unrolled so LDS reads pipeline behind the 4-cyc FMA dependence chain)
    float acc = 0.0f;
    if (t < 40) {
      if (c4 < 3) {
#pragma unroll 16
        for (int i = 0; i < 288; i++) acc = fmaf(sch[i], wch[i], acc);
      } else {
#pragma unroll 17
        for (int i = 0; i < 136; i++) acc = fmaf(sch[i], wch[i], acc);
      }
    }

    // phase C: wave-0 shfl combine (exact ordered adds) + recurrence + store
    if (t < 64) {
      float p0 = __shfl(acc, o4, 64);        // chain (o4, c=0)
      float p1 = __shfl(acc, 10 + o4, 64);   // chain (o4, c=1)
      float p2 = __shfl(acc, 20 + o4, 64);   // chain (o4, c=2)
      float p3 = __shfl(acc, 30 + o4, 64);   // chain (o4, c=3)
      if (t < 10) {
        float tot = p0;                      // C = P0
        tot = __fadd_rn(tot, p1);            // C += P1
        tot = __fadd_rn(tot, p2);            // C += P2
        tot = __fadd_rn(tot, p3);            // C += P3
        float c2 = __fadd_rn(tot, fc2_b[t]); // + bias
        float r2 = (m2 > 1.0f) ? 1.0f : 0.0f;
        float u1 = __fmul_rn(0.95f, m2);
        float u2 = __fadd_rn(u1, c2);
        m2 = __fsub_rn(u2, r2);
        out[s * 5120 + b * 10 + t] = (m2 > 1.0f) ? 1.0f : 0.0f;  // spk2
        out[51200 + s * 5120 + b * 10 + t] = m2;                  // mem2
      }
    }
    __syncthreads();  // spkp fully consumed before next step's phase A
  }
}

// ---------------------------------------------------------------------------
// Launch. Workspace (39.1 MB peak, aliased):
//   part [0, 30.72M)      — fc1 panel partials [15,512,1000] fp32
//   p1   [0, 16M)         — conv1 out (dead before fc1 writes part)
//   h    [30.72M, 39.1M)  — conv2 out (live through fc1, above part)
// ---------------------------------------------------------------------------
extern "C" void kernel_launch(void* const* d_in, const int* in_sizes, int n_in,
                              void* d_out, int out_size, void* d_ws,
                              size_t ws_size, hipStream_t stream) {
  const float* x   = (const float*)d_in[0];
  const float* c1w = (const float*)d_in[1];
  const float* c1b = (const float*)d_in[2];
  const float* c2w = (const float*)d_in[3];
  const float* c2b = (const float*)d_in[4];
  const float* f1w = (const float*)d_in[5];
  const float* f1b = (const float*)d_in[6];
  const float* f2w = (const float*)d_in[7];
  const float* f2b = (const float*)d_in[8];
  float* out = (float*)d_out;

  char* ws = (char*)d_ws;
  float* part = (float*)(ws);                        // [15,512,1000] = 30.72 MB
  float* p1   = (float*)(ws);                        // [512,32,256] alias (dead early)
  float* h    = (float*)(ws + (size_t)15 * 512 * 1000 * 4);  // [512,4096]

  conv1_pool<<<512, 256, 0, stream>>>(x, c1w, c1b, p1);
  conv2_pool<<<512, 256, 0, stream>>>(p1, c2w, c2b, h);
  fc1_panel<<<dim3(4, 16, 15), 256, 0, stream>>>(h, f1w, part);
  snn_loop<<<512, 256, 0, stream>>>(part, f1b, f2w, f2b, out);
}

// Round 11
// 267.407 us; speedup vs baseline: 1.9298x; 1.0748x over previous
//
#include <hip/hip_runtime.h>

// ---------------------------------------------------------------------------
// R11: numerics frozen from R6 (PASS, absmax 1.95e-3). Perf target: conv2
// (93 us, VALUBusy 36% -> 64% latency-stalled on scattered per-oc weight
// loads, 16 lines x 1152B apart per K-node). Fix: pre-pass transposes conv2
// weights into per-wave K-major layout wt[((g*32+ic)*9+kk)*16 + i] so each
// wave reads ONE contiguous wave-uniform 64B block per K-node (sequential
// s_load_dwordx16, prefetchable). Pure copy -> bit-identical numerics.
// conv1 / fc1_panel / snn_loop unchanged from R10.
// ---------------------------------------------------------------------------

// ---------------------------------------------------------------------------
// Kernel 0: conv2 weight transpose. w[oc][ic][ky][kx] (oc=g*16+i) ->
// wt[((g*32+ic)*9+kk)*16 + i]. 18432 elements, trivial.
// ---------------------------------------------------------------------------
__global__ void __launch_bounds__(256) conv2_wt(
    const float* __restrict__ w, float* __restrict__ wt) {
  int tid = blockIdx.x * 256 + threadIdx.x;
  if (tid >= 64 * 288) return;
  int i = tid & 15;
  int node = tid >> 4;
  int kk = node % 9;
  int gic = node / 9;
  int ic = gic & 31, g = gic >> 5;
  wt[tid] = w[(size_t)(g * 16 + i) * 288 + ic * 9 + kk];
}

// ---------------------------------------------------------------------------
// Kernel 1: conv1 (3->32) + bias + ReLU + 2x2 maxpool. UNCHANGED.
// Chain order: ky -> kx -> ic (ic innermost).
// ---------------------------------------------------------------------------
__global__ void __launch_bounds__(256) conv1_pool(
    const float* __restrict__ x, const float* __restrict__ w,
    const float* __restrict__ bias, float* __restrict__ p1) {
  const int b = blockIdx.x;
  __shared__ float sx[3 * 34 * 34];
  const float* xb = x + (size_t)b * 3072;
  for (int i = threadIdx.x; i < 3 * 34 * 34; i += 256) sx[i] = 0.0f;
  __syncthreads();
  for (int i = threadIdx.x; i < 3072; i += 256) {
    int ic = i >> 10, y = (i >> 5) & 31, xx = i & 31;
    sx[ic * 1156 + (y + 1) * 34 + (xx + 1)] = xb[i];
  }
  __syncthreads();

  const int px = threadIdx.x & 15, py = threadIdx.x >> 4;
  float xr[3][4][4];
#pragma unroll
  for (int ic = 0; ic < 3; ic++)
#pragma unroll
    for (int r = 0; r < 4; r++)
#pragma unroll
      for (int c = 0; c < 4; c++)
        xr[ic][r][c] = sx[ic * 1156 + (2 * py + r) * 34 + (2 * px + c)];

  float* outp = p1 + (size_t)b * 8192 + py * 16 + px;
  for (int oc = 0; oc < 32; oc++) {
    const float* wo = w + oc * 27;
    float a0 = 0.0f, a1 = 0.0f, a2 = 0.0f, a3 = 0.0f;
#pragma unroll
    for (int ky = 0; ky < 3; ky++)
#pragma unroll
      for (int kx = 0; kx < 3; kx++)
#pragma unroll
        for (int ic = 0; ic < 3; ic++) {  // ic innermost (HWIO im2col order)
          float wv = wo[ic * 9 + ky * 3 + kx];
          a0 = fmaf(wv, xr[ic][ky][kx], a0);
          a1 = fmaf(wv, xr[ic][ky][kx + 1], a1);
          a2 = fmaf(wv, xr[ic][ky + 1][kx], a2);
          a3 = fmaf(wv, xr[ic][ky + 1][kx + 1], a3);
        }
    float bv = bias[oc];
    a0 = fmaxf(__fadd_rn(a0, bv), 0.0f);
    a1 = fmaxf(__fadd_rn(a1, bv), 0.0f);
    a2 = fmaxf(__fadd_rn(a2, bv), 0.0f);
    a3 = fmaxf(__fadd_rn(a3, bv), 0.0f);
    outp[oc * 256] = fmaxf(fmaxf(a0, a1), fmaxf(a2, a3));
  }
}

// ---------------------------------------------------------------------------
// Kernel 2: conv2 (32->64) + bias + ReLU + pool. Weight reads now from the
// transposed wt: one contiguous wave-uniform 64B block per (ky,kx,ic) node.
// FMA chain order per accumulator unchanged: ky -> kx -> ic (ic fastest).
// ---------------------------------------------------------------------------
__global__ void __launch_bounds__(256) conv2_pool(
    const float* __restrict__ p1, const float* __restrict__ wt,
    const float* __restrict__ bias, float* __restrict__ p2) {
  const int b = blockIdx.x;
  __shared__ float sx[32 * 18 * 18];  // 41472 B
  const float* xb = p1 + (size_t)b * 8192;
  for (int i = threadIdx.x; i < 32 * 18 * 18; i += 256) sx[i] = 0.0f;
  __syncthreads();
  for (int i = threadIdx.x; i < 8192; i += 256) {
    int ic = i >> 8, y = (i >> 4) & 15, xx = i & 15;
    sx[ic * 324 + (y + 1) * 18 + (xx + 1)] = xb[i];
  }
  __syncthreads();

  const int t = threadIdx.x;
  const int px = t & 7, py = (t >> 3) & 7;
  const int g = __builtin_amdgcn_readfirstlane(t >> 6);  // wave 0..3
  const float* wg = wt + (size_t)g * 32 * 9 * 16;        // wave's K-stream

  float acc[16][4];
#pragma unroll
  for (int i = 0; i < 16; i++)
    acc[i][0] = acc[i][1] = acc[i][2] = acc[i][3] = 0.0f;

#pragma unroll
  for (int ky = 0; ky < 3; ky++) {
#pragma unroll
    for (int kx = 0; kx < 3; kx++) {
      const int r0 = (2 * py + ky) * 18 + 2 * px + kx;
      const int r1 = r0 + 18;
#pragma unroll 4
      for (int ic = 0; ic < 32; ic++) {  // ic innermost (chain order)
        float x00 = sx[ic * 324 + r0];
        float x01 = sx[ic * 324 + r0 + 1];
        float x10 = sx[ic * 324 + r1];
        float x11 = sx[ic * 324 + r1 + 1];
        const float* wp = wg + (size_t)(ic * 9 + ky * 3 + kx) * 16;
#pragma unroll
        for (int i = 0; i < 16; i++) {
          float wv = wp[i];  // wave-uniform contiguous -> s_load
          acc[i][0] = fmaf(wv, x00, acc[i][0]);
          acc[i][1] = fmaf(wv, x01, acc[i][1]);
          acc[i][2] = fmaf(wv, x10, acc[i][2]);
          acc[i][3] = fmaf(wv, x11, acc[i][3]);
        }
      }
    }
  }

  float* outb = p2 + (size_t)b * 4096;
#pragma unroll
  for (int i = 0; i < 16; i++) {
    float bv = bias[g * 16 + i];
    float a0 = fmaxf(__fadd_rn(acc[i][0], bv), 0.0f);
    float a1 = fmaxf(__fadd_rn(acc[i][1], bv), 0.0f);
    float a2 = fmaxf(__fadd_rn(acc[i][2], bv), 0.0f);
    float a3 = fmaxf(__fadd_rn(acc[i][3], bv), 0.0f);
    outb[(g * 16 + i) * 64 + py * 8 + px] = fmaxf(fmaxf(a0, a1), fmaxf(a2, a3));
  }
}

// ---------------------------------------------------------------------------
// Kernel 3: fc1 panel GEMM, split-K over Eigen kc=288 panels. UNCHANGED.
// ---------------------------------------------------------------------------
__global__ void __launch_bounds__(256) fc1_panel(
    const float* __restrict__ A,   // h [512,4096]
    const float* __restrict__ W,   // [1000,4096]
    float* __restrict__ part) {    // [15,512,1000]
  __shared__ __align__(16) float As[16][132];  // 8448 B
  __shared__ __align__(16) float Bs[16][68];   // 4352 B
  const int t = threadIdx.x;
  const int m0 = blockIdx.x * 128, n0 = blockIdx.y * 64;
  const int z = blockIdx.z;
  const int k0 = z * 288;
  const int L = (z == 14) ? 64 : 288;

  const int lmA = t >> 1, lkA = (t & 1) * 8;
  const int lmB = t >> 2, lkB = (t & 3) * 4;
  const int nr = n0 + lmB;
  const float* Ap = A + (size_t)(m0 + lmA) * 4096 + k0 + lkA;
  const float* Bp = W + (size_t)(nr < 1000 ? nr : 0) * 4096 + k0 + lkB;
  const int tx = t & 15, ty = t >> 4;

  float acc[8][4];
#pragma unroll
  for (int i = 0; i < 8; i++)
#pragma unroll
    for (int j = 0; j < 4; j++) acc[i][j] = 0.0f;

  for (int kk = 0; kk < L; kk += 16) {
    float4 a0 = *(const float4*)Ap;
    float4 a1 = *(const float4*)(Ap + 4);
    float4 b4 = *(const float4*)Bp;
    As[lkA + 0][lmA] = a0.x; As[lkA + 1][lmA] = a0.y;
    As[lkA + 2][lmA] = a0.z; As[lkA + 3][lmA] = a0.w;
    As[lkA + 4][lmA] = a1.x; As[lkA + 5][lmA] = a1.y;
    As[lkA + 6][lmA] = a1.z; As[lkA + 7][lmA] = a1.w;
    Bs[lkB + 0][lmB] = b4.x; Bs[lkB + 1][lmB] = b4.y;
    Bs[lkB + 2][lmB] = b4.z; Bs[lkB + 3][lmB] = b4.w;
    __syncthreads();
#pragma unroll
    for (int k = 0; k < 16; k++) {
      float4 av0 = *(const float4*)&As[k][tx * 8];
      float4 av1 = *(const float4*)&As[k][tx * 8 + 4];
      float4 bv = *(const float4*)&Bs[k][ty * 4];
      float am[8] = {av0.x, av0.y, av0.z, av0.w, av1.x, av1.y, av1.z, av1.w};
#pragma unroll
      for (int i = 0; i < 8; i++) {
        acc[i][0] = fmaf(am[i], bv.x, acc[i][0]);
        acc[i][1] = fmaf(am[i], bv.y, acc[i][1]);
        acc[i][2] = fmaf(am[i], bv.z, acc[i][2]);
        acc[i][3] = fmaf(am[i], bv.w, acc[i][3]);
      }
    }
    __syncthreads();
    Ap += 16; Bp += 16;
  }

  float* pp = part + (size_t)z * 512000;
#pragma unroll
  for (int i = 0; i < 8; i++) {
    const int m = m0 + tx * 8 + i;
#pragma unroll
    for (int j = 0; j < 4; j++) {
      const int n = n0 + ty * 4 + j;
      if (n < 1000) pp[(size_t)m * 1000 + n] = acc[i][j];
    }
  }
}

// ---------------------------------------------------------------------------
// Kernel 4: fused 10-step SNN. UNCHANGED from R10 (latency-optimized,
// stride-289 LDS panels, unrolled chains, shfl combine).
// ---------------------------------------------------------------------------
__global__ void __launch_bounds__(256) snn_loop(
    const float* __restrict__ part,   // [15,512,1000]
    const float* __restrict__ fc1_b,  // [1000]
    const float* __restrict__ fc2_w,  // [10,1000]
    const float* __restrict__ fc2_b,  // [10]
    float* __restrict__ out) {        // [102400]
  const int b = blockIdx.x;
  const int t = threadIdx.x;
  __shared__ float pw[40 * 289];   // 46240 B
  __shared__ float spkp[4 * 289];  //  4624 B

  for (int i = t; i < 40 * 289; i += 256) {
    int chain = i / 289, ii = i - chain * 289;
    int o = chain % 10, c = chain / 10;
    int len = (c == 3) ? 136 : 288;
    pw[i] = (ii < len) ? fc2_w[o * 1000 + c * 288 + ii] : 0.0f;
  }

  float cur1[4], mem1[4];
#pragma unroll
  for (int q = 0; q < 4; q++) {
    int j = t + q * 256;
    float c = 0.0f;
    if (j < 1000) {
      const float* pb = part + (size_t)b * 1000 + j;
      float tot = pb[0];
#pragma unroll
      for (int p = 1; p < 15; p++)
        tot = __fadd_rn(tot, pb[(size_t)p * 512000]);
      c = __fadd_rn(tot, fc1_b[j]);
    }
    cur1[q] = c;
    mem1[q] = 0.0f;
  }
  float m2 = 0.0f;  // live only for t < 10
  __syncthreads();

  const int o4 = t % 10, c4 = t / 10;  // chain (o4, c4) for t < 40
  const float* wch = &pw[(c4 * 10 + o4) * 289];
  const float* sch = &spkp[c4 * 289];

  for (int s = 0; s < 10; s++) {
#pragma unroll
    for (int q = 0; q < 4; q++) {
      int j = t + q * 256;
      float m = mem1[q];
      float reset = (m > 1.0f) ? 1.0f : 0.0f;
      float t1 = __fmul_rn(0.95f, m);
      float t2 = __fadd_rn(t1, cur1[q]);
      m = __fsub_rn(t2, reset);
      mem1[q] = m;
      if (j < 1000) {
        int pc = (j >= 864) ? 3 : ((j >= 576) ? 2 : ((j >= 288) ? 1 : 0));
        spkp[pc * 289 + (j - pc * 288)] = (m > 1.0f) ? 1.0f : 0.0f;
      }
    }
    __syncthreads();

    float acc = 0.0f;
    if (t < 40) {
      if (c4 < 3) {
#pragma unroll 16
        for (int i = 0; i < 288; i++) acc = fmaf(sch[i], wch[i], acc);
      } else {
#pragma unroll 17
        for (int i = 0; i < 136; i++) acc = fmaf(sch[i], wch[i], acc);
      }
    }

    if (t < 64) {
      float p0 = __shfl(acc, o4, 64);
      float p1 = __shfl(acc, 10 + o4, 64);
      float p2 = __shfl(acc, 20 + o4, 64);
      float p3 = __shfl(acc, 30 + o4, 64);
      if (t < 10) {
        float tot = p0;
        tot = __fadd_rn(tot, p1);
        tot = __fadd_rn(tot, p2);
        tot = __fadd_rn(tot, p3);
        float c2 = __fadd_rn(tot, fc2_b[t]);
        float r2 = (m2 > 1.0f) ? 1.0f : 0.0f;
        float u1 = __fmul_rn(0.95f, m2);
        float u2 = __fadd_rn(u1, c2);
        m2 = __fsub_rn(u2, r2);
        out[s * 5120 + b * 10 + t] = (m2 > 1.0f) ? 1.0f : 0.0f;  // spk2
        out[51200 + s * 5120 + b * 10 + t] = m2;                  // mem2
      }
    }
    __syncthreads();
  }
}

// ---------------------------------------------------------------------------
// Launch. Workspace (39.2 MB peak, aliased):
//   part [0, 30.72M)       — fc1 panel partials [15,512,1000] fp32
//   p1   [0, 16M)          — conv1 out (dead before fc1 writes part)
//   h    [30.72M, 39.1M)   — conv2 out (live through fc1)
//   wt   [39.1M, 39.2M)    — transposed conv2 weights (18432 fp32)
// ---------------------------------------------------------------------------
extern "C" void kernel_launch(void* const* d_in, const int* in_sizes, int n_in,
                              void* d_out, int out_size, void* d_ws,
                              size_t ws_size, hipStream_t stream) {
  const float* x   = (const float*)d_in[0];
  const float* c1w = (const float*)d_in[1];
  const float* c1b = (const float*)d_in[2];
  const float* c2w = (const float*)d_in[3];
  const float* c2b = (const float*)d_in[4];
  const float* f1w = (const float*)d_in[5];
  const float* f1b = (const float*)d_in[6];
  const float* f2w = (const float*)d_in[7];
  const float* f2b = (const float*)d_in[8];
  float* out = (float*)d_out;

  char* ws = (char*)d_ws;
  float* part = (float*)(ws);                        // [15,512,1000] = 30.72 MB
  float* p1   = (float*)(ws);                        // alias (dead early)
  float* h    = (float*)(ws + (size_t)15 * 512 * 1000 * 4);       // [512,4096]
  float* wt   = (float*)(ws + (size_t)15 * 512 * 1000 * 4 + (size_t)512 * 4096 * 4);

  conv2_wt<<<72, 256, 0, stream>>>(c2w, wt);
  conv1_pool<<<512, 256, 0, stream>>>(x, c1w, c1b, p1);
  conv2_pool<<<512, 256, 0, stream>>>(p1, wt, c2b, h);
  fc1_panel<<<dim3(4, 16, 15), 256, 0, stream>>>(h, f1w, part);
  snn_loop<<<512, 256, 0, stream>>>(part, f1b, f2w, f2b, out);
}